// Round 1
// baseline (5651.258 us; speedup 1.0000x reference)
//
#include <hip/hip_runtime.h>
#include <math.h>

#define NODES_C 256
#define NEG_SLOPE 0.2f

// ---------------- K1: h = x @ W (fp32, LDS-tiled) ----------------
// block = 256 threads, each block computes 32 rows x 256 cols.
__global__ __launch_bounds__(256) void k_gemm_xw(const float* __restrict__ x,
                                                 const float* __restrict__ W,
                                                 float* __restrict__ h, int n) {
    __shared__ float xs[32 * NODES_C];
    const int block_row = blockIdx.x * 32;
    const int tid = threadIdx.x;
    const int nrow = min(32, n - block_row);

    // stage x tile into LDS (float4, coalesced)
    {
        const float4* xg = (const float4*)(x + (size_t)block_row * NODES_C);
        float4* xl = (float4*)xs;
        const int total4 = nrow * (NODES_C / 4);
        for (int i = tid; i < total4; i += 256) xl[i] = xg[i];
    }
    __syncthreads();

    const int c = tid;  // this thread's output column
    float acc[32];
#pragma unroll
    for (int r = 0; r < 32; ++r) acc[r] = 0.f;

    for (int k = 0; k < NODES_C; k += 4) {
        const float w0 = W[(k + 0) * NODES_C + c];
        const float w1 = W[(k + 1) * NODES_C + c];
        const float w2 = W[(k + 2) * NODES_C + c];
        const float w3 = W[(k + 3) * NODES_C + c];
#pragma unroll
        for (int r = 0; r < 32; ++r) {
            const float4 xv = *(const float4*)&xs[r * NODES_C + k];  // broadcast
            acc[r] = fmaf(xv.x, w0, acc[r]);
            acc[r] = fmaf(xv.y, w1, acc[r]);
            acc[r] = fmaf(xv.z, w2, acc[r]);
            acc[r] = fmaf(xv.w, w3, acc[r]);
        }
    }
    for (int r = 0; r < nrow; ++r)
        h[(size_t)(block_row + r) * NODES_C + c] = acc[r];
}

// ---------------- K2: per-node a_s, a_d; init emax (self-loop), denom=0 ----
// one wave (64 lanes) per node; lane handles 4 channels via float4.
__global__ __launch_bounds__(256) void k_node_att(const float* __restrict__ h,
                                                  const float* __restrict__ att_src,
                                                  const float* __restrict__ att_dst,
                                                  float* __restrict__ a_s,
                                                  float* __restrict__ a_d,
                                                  float* __restrict__ emax,
                                                  float* __restrict__ denom, int n) {
    const int node = (int)((blockIdx.x * (size_t)blockDim.x + threadIdx.x) >> 6);
    const int lane = threadIdx.x & 63;
    if (node >= n) return;
    const float4 hv = ((const float4*)(h + (size_t)node * NODES_C))[lane];
    const float4 as4 = ((const float4*)att_src)[lane];
    const float4 ad4 = ((const float4*)att_dst)[lane];
    float s = hv.x * as4.x + hv.y * as4.y + hv.z * as4.z + hv.w * as4.w;
    float d = hv.x * ad4.x + hv.y * ad4.y + hv.z * ad4.z + hv.w * ad4.w;
#pragma unroll
    for (int off = 32; off; off >>= 1) {
        s += __shfl_down(s, off);
        d += __shfl_down(d, off);
    }
    if (lane == 0) {
        a_s[node] = s;
        a_d[node] = d;
        float e = s + d;                       // self-loop logit
        e = e > 0.f ? e : NEG_SLOPE * e;
        emax[node] = e;                        // max is at least the self edge
        denom[node] = 0.f;
    }
}

// ---------------- K3: per-edge atomic max of logits into emax[dst] --------
__device__ inline void atomicMaxFloat(float* addr, float v) {
    if (v >= 0.f)
        atomicMax((int*)addr, __float_as_int(v));
    else
        atomicMin((unsigned int*)addr, __float_as_uint(v));
}

__global__ __launch_bounds__(256) void k_edge_max(const int* __restrict__ src,
                                                  const int* __restrict__ dst,
                                                  const float* __restrict__ a_s,
                                                  const float* __restrict__ a_d,
                                                  float* __restrict__ emax, int E) {
    const int i = blockIdx.x * blockDim.x + threadIdx.x;
    if (i >= E) return;
    const int s = src[i], d = dst[i];
    float e = a_s[s] + a_d[d];
    e = e > 0.f ? e : NEG_SLOPE * e;
    atomicMaxFloat(&emax[d], e);
}

// ---------------- K4: per-edge w = exp(e - emax[dst]); denom += w ---------
__global__ __launch_bounds__(256) void k_edge_exp(const int* __restrict__ src,
                                                  const int* __restrict__ dst,
                                                  const float* __restrict__ a_s,
                                                  const float* __restrict__ a_d,
                                                  const float* __restrict__ emax,
                                                  float* __restrict__ denom,
                                                  float* __restrict__ wbuf, int E) {
    const int i = blockIdx.x * blockDim.x + threadIdx.x;
    if (i >= E) return;
    const int s = src[i], d = dst[i];
    float e = a_s[s] + a_d[d];
    e = e > 0.f ? e : NEG_SLOPE * e;
    const float w = __expf(e - emax[d]);
    wbuf[i] = w;
    atomicAdd(&denom[d], w);
}

// ---------------- K5: finalize denom with self term; out = bias + a*h -----
// one wave per node
__global__ __launch_bounds__(256) void k_node_fin(const float* __restrict__ h,
                                                  const float* __restrict__ a_s,
                                                  const float* __restrict__ a_d,
                                                  const float* __restrict__ emax,
                                                  float* __restrict__ denom,
                                                  const float* __restrict__ bias,
                                                  float* __restrict__ out, int n) {
    const int node = (int)((blockIdx.x * (size_t)blockDim.x + threadIdx.x) >> 6);
    const int lane = threadIdx.x & 63;
    if (node >= n) return;
    float e = a_s[node] + a_d[node];
    e = e > 0.f ? e : NEG_SLOPE * e;
    const float w = __expf(e - emax[node]);
    const float dn = denom[node] + w;   // include self-loop in the softmax sum
    if (lane == 0) denom[node] = dn;
    const float alpha = w / dn;
    const float4 hv = ((const float4*)(h + (size_t)node * NODES_C))[lane];
    const float4 b4 = ((const float4*)bias)[lane];
    float4 o;
    o.x = b4.x + alpha * hv.x;
    o.y = b4.y + alpha * hv.y;
    o.z = b4.z + alpha * hv.z;
    o.w = b4.w + alpha * hv.w;
    ((float4*)(out + (size_t)node * NODES_C))[lane] = o;
}

// ---------------- K6: per-edge scatter out[dst] += alpha * h[src] ---------
// one wave per edge; lane handles 4 channels.
__global__ __launch_bounds__(256) void k_edge_scatter(const int* __restrict__ src,
                                                      const int* __restrict__ dst,
                                                      const float* __restrict__ wbuf,
                                                      const float* __restrict__ denom,
                                                      const float* __restrict__ h,
                                                      float* __restrict__ out, int E) {
    const int e = (int)((blockIdx.x * (size_t)blockDim.x + threadIdx.x) >> 6);
    const int lane = threadIdx.x & 63;
    if (e >= E) return;
    const int s = src[e], d = dst[e];
    const float alpha = wbuf[e] / denom[d];
    const float4 hv = ((const float4*)(h + (size_t)s * NODES_C))[lane];
    float* op = out + (size_t)d * NODES_C + lane * 4;
    atomicAdd(op + 0, alpha * hv.x);
    atomicAdd(op + 1, alpha * hv.y);
    atomicAdd(op + 2, alpha * hv.z);
    atomicAdd(op + 3, alpha * hv.w);
}

extern "C" void kernel_launch(void* const* d_in, const int* in_sizes, int n_in,
                              void* d_out, int out_size, void* d_ws, size_t ws_size,
                              hipStream_t stream) {
    const float* x       = (const float*)d_in[0];
    const int*   edge    = (const int*)d_in[1];   // [2, E] flat: row0=src, row1=dst
    const float* W       = (const float*)d_in[2];
    const float* att_src = (const float*)d_in[3];
    const float* att_dst = (const float*)d_in[4];
    const float* bias    = (const float*)d_in[5];
    float* out = (float*)d_out;

    const int n = in_sizes[0] / NODES_C;      // 50000
    const int E = in_sizes[1] / 2;            // 1600000
    const int* src = edge;
    const int* dst = edge + E;

    // workspace layout (floats)
    float* ws = (float*)d_ws;
    float* h     = ws;                         // n*256
    float* a_s   = h + (size_t)n * NODES_C;    // n
    float* a_d   = a_s + n;                    // n
    float* emax  = a_d + n;                    // n
    float* denom = emax + n;                   // n
    float* wbuf  = denom + n;                  // E

    // K1: h = x @ W
    k_gemm_xw<<<(n + 31) / 32, 256, 0, stream>>>(x, W, h, n);
    // K2: per-node attention terms, emax/denom init
    k_node_att<<<(n + 3) / 4, 256, 0, stream>>>(h, att_src, att_dst, a_s, a_d, emax, denom, n);
    // K3: edge max
    k_edge_max<<<(E + 255) / 256, 256, 0, stream>>>(src, dst, a_s, a_d, emax, E);
    // K4: edge exp + denom
    k_edge_exp<<<(E + 255) / 256, 256, 0, stream>>>(src, dst, a_s, a_d, emax, denom, wbuf, E);
    // K5: finalize denom (self term), init out = bias + alpha_self*h
    k_node_fin<<<(n + 3) / 4, 256, 0, stream>>>(h, a_s, a_d, emax, denom, bias, out, n);
    // K6: scatter messages
    k_edge_scatter<<<(E + 3) / 4, 256, 0, stream>>>(src, dst, wbuf, denom, h, out, E);
}

// Round 2
// 647.355 us; speedup vs baseline: 8.7298x; 8.7298x over previous
//
#include <hip/hip_runtime.h>
#include <math.h>

#define NODES_C 256
#define NEG_SLOPE 0.2f

// ---------------- K1: h = x @ W (fp32, LDS-tiled) ----------------
__global__ __launch_bounds__(256) void k_gemm_xw(const float* __restrict__ x,
                                                 const float* __restrict__ W,
                                                 float* __restrict__ h, int n) {
    __shared__ float xs[32 * NODES_C];
    const int block_row = blockIdx.x * 32;
    const int tid = threadIdx.x;
    const int nrow = min(32, n - block_row);

    {
        const float4* xg = (const float4*)(x + (size_t)block_row * NODES_C);
        float4* xl = (float4*)xs;
        const int total4 = nrow * (NODES_C / 4);
        for (int i = tid; i < total4; i += 256) xl[i] = xg[i];
    }
    __syncthreads();

    const int c = tid;
    float acc[32];
#pragma unroll
    for (int r = 0; r < 32; ++r) acc[r] = 0.f;

    for (int k = 0; k < NODES_C; k += 4) {
        const float w0 = W[(k + 0) * NODES_C + c];
        const float w1 = W[(k + 1) * NODES_C + c];
        const float w2 = W[(k + 2) * NODES_C + c];
        const float w3 = W[(k + 3) * NODES_C + c];
#pragma unroll
        for (int r = 0; r < 32; ++r) {
            const float4 xv = *(const float4*)&xs[r * NODES_C + k];
            acc[r] = fmaf(xv.x, w0, acc[r]);
            acc[r] = fmaf(xv.y, w1, acc[r]);
            acc[r] = fmaf(xv.z, w2, acc[r]);
            acc[r] = fmaf(xv.w, w3, acc[r]);
        }
    }
    for (int r = 0; r < nrow; ++r)
        h[(size_t)(block_row + r) * NODES_C + c] = acc[r];
}

// ---------------- K2: per-node a_s, a_d -----------------------------------
__global__ __launch_bounds__(256) void k_node_att(const float* __restrict__ h,
                                                  const float* __restrict__ att_src,
                                                  const float* __restrict__ att_dst,
                                                  float* __restrict__ a_s,
                                                  float* __restrict__ a_d, int n) {
    const int node = (int)((blockIdx.x * (size_t)blockDim.x + threadIdx.x) >> 6);
    const int lane = threadIdx.x & 63;
    if (node >= n) return;
    const float4 hv = ((const float4*)(h + (size_t)node * NODES_C))[lane];
    const float4 as4 = ((const float4*)att_src)[lane];
    const float4 ad4 = ((const float4*)att_dst)[lane];
    float s = hv.x * as4.x + hv.y * as4.y + hv.z * as4.z + hv.w * as4.w;
    float d = hv.x * ad4.x + hv.y * ad4.y + hv.z * ad4.z + hv.w * ad4.w;
#pragma unroll
    for (int off = 32; off; off >>= 1) {
        s += __shfl_down(s, off);
        d += __shfl_down(d, off);
    }
    if (lane == 0) {
        a_s[node] = s;
        a_d[node] = d;
    }
}

// ---------------- K3: degree count ----------------------------------------
__global__ __launch_bounds__(256) void k_count(const int* __restrict__ dst,
                                               int* __restrict__ deg, int E) {
    const int i = blockIdx.x * blockDim.x + threadIdx.x;
    if (i < E) atomicAdd(&deg[dst[i]], 1);
}

// ---------------- K4: single-block exclusive scan over n elements ---------
// 1024 threads, chunked. Writes rowptr[0..n] and cursor[0..n-1].
__global__ __launch_bounds__(1024) void k_scan(const int* __restrict__ deg,
                                               int* __restrict__ rowptr,
                                               int* __restrict__ cursor, int n) {
    __shared__ int wsum[16];
    __shared__ int carry_s;
    const int tid = threadIdx.x;
    const int lane = tid & 63, wid = tid >> 6;
    if (tid == 0) carry_s = 0;
    __syncthreads();
    for (int base = 0; base < n; base += 1024) {
        const int i = base + tid;
        const int orig = (i < n) ? deg[i] : 0;
        int v = orig;
        // inclusive scan within wave
#pragma unroll
        for (int off = 1; off < 64; off <<= 1) {
            int t = __shfl_up(v, off);
            if (lane >= off) v += t;
        }
        if (lane == 63) wsum[wid] = v;
        __syncthreads();
        if (wid == 0 && lane < 16) {
            int s = wsum[lane];
#pragma unroll
            for (int off = 1; off < 16; off <<= 1) {
                int t = __shfl_up(s, off);
                if (lane >= off) s += t;
            }
            wsum[lane] = s;
        }
        __syncthreads();
        const int carry = carry_s;
        const int incl = v + (wid > 0 ? wsum[wid - 1] : 0) + carry;
        if (i < n) {
            rowptr[i] = incl - orig;
            cursor[i] = incl - orig;
        }
        __syncthreads();
        if (tid == 1023) carry_s = incl;  // chunk total (padding adds 0)
        __syncthreads();
    }
    if (tid == 0) rowptr[n] = carry_s;
}

// ---------------- K5: permute edges into CSR slots ------------------------
__global__ __launch_bounds__(256) void k_permute(const int* __restrict__ src,
                                                 const int* __restrict__ dst,
                                                 const float* __restrict__ a_s,
                                                 const float* __restrict__ a_d,
                                                 int* __restrict__ cursor,
                                                 int* __restrict__ ssrc,
                                                 float* __restrict__ se, int E) {
    const int i = blockIdx.x * blockDim.x + threadIdx.x;
    if (i >= E) return;
    const int s = src[i], d = dst[i];
    const int pos = atomicAdd(&cursor[d], 1);
    ssrc[pos] = s;
    float e = a_s[s] + a_d[d];
    e = e > 0.f ? e : NEG_SLOPE * e;
    se[pos] = e;
}

// ---------------- K6: fused gather: softmax + weighted sum + bias ---------
// one wave per destination node; lane owns 4 channels (float4).
__global__ __launch_bounds__(256) void k_gather(const int* __restrict__ rowptr,
                                                const int* __restrict__ ssrc,
                                                const float* __restrict__ se,
                                                const float* __restrict__ h,
                                                const float* __restrict__ a_s,
                                                const float* __restrict__ a_d,
                                                const float* __restrict__ bias,
                                                float* __restrict__ out, int n) {
    const int node = (int)((blockIdx.x * (size_t)blockDim.x + threadIdx.x) >> 6);
    const int lane = threadIdx.x & 63;
    if (node >= n) return;
    const int start = rowptr[node];
    const int end = rowptr[node + 1];

    float eself = a_s[node] + a_d[node];
    eself = eself > 0.f ? eself : NEG_SLOPE * eself;

    // pass 1: max over edge logits (self included)
    float m = eself;
    for (int j = start + lane; j < end; j += 64) m = fmaxf(m, se[j]);
#pragma unroll
    for (int off = 32; off; off >>= 1) m = fmaxf(m, __shfl_xor(m, off));

    // pass 2: weights + weighted feature sum
    float denom = 0.f;
    float4 acc = make_float4(0.f, 0.f, 0.f, 0.f);
    for (int jb = start; jb < end; jb += 64) {
        const int nthis = min(64, end - jb);
        int sj = 0;
        float ej = 0.f;
        if (lane < nthis) {
            sj = ssrc[jb + lane];
            ej = se[jb + lane];
        }
        for (int t = 0; t < nthis; ++t) {
            const int s = __shfl(sj, t);
            const float e = __shfl(ej, t);
            const float w = __expf(e - m);
            denom += w;
            const float4 hv = ((const float4*)(h + (size_t)s * NODES_C))[lane];
            acc.x = fmaf(w, hv.x, acc.x);
            acc.y = fmaf(w, hv.y, acc.y);
            acc.z = fmaf(w, hv.z, acc.z);
            acc.w = fmaf(w, hv.w, acc.w);
        }
    }
    // self-loop contribution
    {
        const float w = __expf(eself - m);
        denom += w;
        const float4 hv = ((const float4*)(h + (size_t)node * NODES_C))[lane];
        acc.x = fmaf(w, hv.x, acc.x);
        acc.y = fmaf(w, hv.y, acc.y);
        acc.z = fmaf(w, hv.z, acc.z);
        acc.w = fmaf(w, hv.w, acc.w);
    }
    const float inv = 1.f / denom;
    const float4 b4 = ((const float4*)bias)[lane];
    float4 o;
    o.x = fmaf(acc.x, inv, b4.x);
    o.y = fmaf(acc.y, inv, b4.y);
    o.z = fmaf(acc.z, inv, b4.z);
    o.w = fmaf(acc.w, inv, b4.w);
    ((float4*)(out + (size_t)node * NODES_C))[lane] = o;
}

extern "C" void kernel_launch(void* const* d_in, const int* in_sizes, int n_in,
                              void* d_out, int out_size, void* d_ws, size_t ws_size,
                              hipStream_t stream) {
    const float* x       = (const float*)d_in[0];
    const int*   edge    = (const int*)d_in[1];
    const float* W       = (const float*)d_in[2];
    const float* att_src = (const float*)d_in[3];
    const float* att_dst = (const float*)d_in[4];
    const float* bias    = (const float*)d_in[5];
    float* out = (float*)d_out;

    const int n = in_sizes[0] / NODES_C;   // 50000
    const int E = in_sizes[1] / 2;         // 1600000
    const int* src = edge;
    const int* dst = edge + E;

    // workspace layout
    char* ws = (char*)d_ws;
    float* h      = (float*)ws;                       ws += (size_t)n * NODES_C * 4;  // 51.2 MB
    float* a_s    = (float*)ws;                       ws += (size_t)n * 4;
    float* a_d    = (float*)ws;                       ws += (size_t)n * 4;
    int*   deg    = (int*)ws;                         ws += (size_t)n * 4;
    int*   rowptr = (int*)ws;                         ws += (size_t)(n + 1) * 4;
    int*   cursor = (int*)ws;                         ws += (size_t)n * 4;
    int*   ssrc   = (int*)ws;                         ws += (size_t)E * 4;            // 6.4 MB
    float* se     = (float*)ws;                       ws += (size_t)E * 4;            // 6.4 MB

    // zero degree counters (ws is not re-poisoned between replays)
    hipMemsetAsync(deg, 0, (size_t)n * 4, stream);

    k_gemm_xw<<<(n + 31) / 32, 256, 0, stream>>>(x, W, h, n);
    k_node_att<<<(n + 3) / 4, 256, 0, stream>>>(h, att_src, att_dst, a_s, a_d, n);
    k_count<<<(E + 255) / 256, 256, 0, stream>>>(dst, deg, E);
    k_scan<<<1, 1024, 0, stream>>>(deg, rowptr, cursor, n);
    k_permute<<<(E + 255) / 256, 256, 0, stream>>>(src, dst, a_s, a_d, cursor, ssrc, se, E);
    k_gather<<<(n + 3) / 4, 256, 0, stream>>>(rowptr, ssrc, se, h, a_s, a_d, bias, out, n);
}

// Round 3
// 322.846 us; speedup vs baseline: 17.5045x; 2.0051x over previous
//
#include <hip/hip_runtime.h>
#include <math.h>

#define NODES_C 256
#define NEG_SLOPE 0.2f

typedef __attribute__((ext_vector_type(8))) short short8;
typedef __attribute__((ext_vector_type(4))) float f32x4;

__device__ inline unsigned short f2bf(float f) {   // RNE float->bf16
    unsigned u = __float_as_uint(f);
    u = (u + 0x7fff + ((u >> 16) & 1)) >> 16;
    return (unsigned short)u;
}
__device__ inline float bf2f(unsigned short u) {
    return __uint_as_float((unsigned)u << 16);
}

__device__ inline void gload_lds16(const void* g, void* l) {
    __builtin_amdgcn_global_load_lds(
        (const __attribute__((address_space(1))) unsigned int*)g,
        (__attribute__((address_space(3))) unsigned int*)l, 16, 0, 0);
}

// ---------------- K0a: x (fp32) -> xb (bf16), zero-padded to Mpad rows ----
__global__ __launch_bounds__(256) void k_cvt_x(const float* __restrict__ x,
                                               unsigned short* __restrict__ xb,
                                               int valid4, int total4) {
    const int i = blockIdx.x * 256 + threadIdx.x;
    if (i >= total4) return;
    ushort4 o = {0, 0, 0, 0};
    if (i < valid4) {
        const float4 v = ((const float4*)x)[i];
        o.x = f2bf(v.x); o.y = f2bf(v.y); o.z = f2bf(v.z); o.w = f2bf(v.w);
    }
    ((ushort4*)xb)[i] = o;
}

// ---------------- K0b: W (fp32, [k][n]) -> wt (bf16, [n][k]) --------------
__global__ __launch_bounds__(256) void k_cvt_w(const float* __restrict__ W,
                                               unsigned short* __restrict__ wt) {
    const int i = blockIdx.x * 256 + threadIdx.x;  // 65536 total
    const int nn = i >> 8, kk = i & 255;
    wt[i] = f2bf(W[kk * NODES_C + nn]);
}

// ---------------- K1: h = x @ W via MFMA bf16, 128x128 tile ---------------
// grid: (Mpad/128) * 2 ; block: 256 threads = 4 waves (2x2), wave tile 64x64
__global__ __launch_bounds__(256) void k_gemm_mfma(const unsigned short* __restrict__ xb,
                                                   const unsigned short* __restrict__ wt,
                                                   unsigned short* __restrict__ hb, int n) {
    __shared__ unsigned short Ab[128 * 32];
    __shared__ unsigned short Bb[128 * 32];
    const int tid = threadIdx.x;
    const int lane = tid & 63;
    const int wid = tid >> 6;
    const int wr = wid >> 1, wc = wid & 1;
    const int brow = (blockIdx.x >> 1) * 128;
    const int bcol = (blockIdx.x & 1) * 128;

    f32x4 acc[4][4] = {};

    const int c0 = wid, c1 = wid + 4;            // LDS 1KB chunks this wave stages
    const int srow0 = c0 * 16 + (lane >> 2), srow1 = c1 * 16 + (lane >> 2);
    const int sk = (lane & 3) * 8;
    const int rsel = lane & 15, ksel = (lane >> 4) * 8;

    for (int kk = 0; kk < 256; kk += 32) {
        gload_lds16(xb + (size_t)(brow + srow0) * NODES_C + kk + sk, Ab + c0 * 512);
        gload_lds16(xb + (size_t)(brow + srow1) * NODES_C + kk + sk, Ab + c1 * 512);
        gload_lds16(wt + (size_t)(bcol + srow0) * NODES_C + kk + sk, Bb + c0 * 512);
        gload_lds16(wt + (size_t)(bcol + srow1) * NODES_C + kk + sk, Bb + c1 * 512);
        __syncthreads();
        short8 afrag[4], bfrag[4];
#pragma unroll
        for (int m = 0; m < 4; ++m)
            afrag[m] = *(const short8*)&Ab[(wr * 64 + m * 16 + rsel) * 32 + ksel];
#pragma unroll
        for (int q = 0; q < 4; ++q)
            bfrag[q] = *(const short8*)&Bb[(wc * 64 + q * 16 + rsel) * 32 + ksel];
#pragma unroll
        for (int m = 0; m < 4; ++m)
#pragma unroll
            for (int q = 0; q < 4; ++q)
                acc[m][q] = __builtin_amdgcn_mfma_f32_16x16x32_bf16(afrag[m], bfrag[q], acc[m][q], 0, 0, 0);
        __syncthreads();
    }

    const int rbase = (lane >> 4) * 4;
#pragma unroll
    for (int m = 0; m < 4; ++m) {
#pragma unroll
        for (int j = 0; j < 4; ++j) {
            const int r = brow + wr * 64 + m * 16 + rbase + j;
            if (r < n) {
#pragma unroll
                for (int q = 0; q < 4; ++q)
                    hb[(size_t)r * NODES_C + bcol + wc * 64 + q * 16 + rsel] = f2bf(acc[m][q][j]);
            }
        }
    }
}

// ---------------- K2: per-node a_s, a_d from bf16 h -----------------------
__global__ __launch_bounds__(256) void k_node_att(const unsigned short* __restrict__ hb,
                                                  const float* __restrict__ att_src,
                                                  const float* __restrict__ att_dst,
                                                  float* __restrict__ a_s,
                                                  float* __restrict__ a_d, int n) {
    const int node = (int)((blockIdx.x * (size_t)blockDim.x + threadIdx.x) >> 6);
    const int lane = threadIdx.x & 63;
    if (node >= n) return;
    const ushort4 hv = ((const ushort4*)(hb + (size_t)node * NODES_C))[lane];
    const float4 as4 = ((const float4*)att_src)[lane];
    const float4 ad4 = ((const float4*)att_dst)[lane];
    const float h0 = bf2f(hv.x), h1 = bf2f(hv.y), h2 = bf2f(hv.z), h3 = bf2f(hv.w);
    float s = h0 * as4.x + h1 * as4.y + h2 * as4.z + h3 * as4.w;
    float d = h0 * ad4.x + h1 * ad4.y + h2 * ad4.z + h3 * ad4.w;
#pragma unroll
    for (int off = 32; off; off >>= 1) {
        s += __shfl_down(s, off);
        d += __shfl_down(d, off);
    }
    if (lane == 0) {
        a_s[node] = s;
        a_d[node] = d;
    }
}

// ---------------- K3: degree count ----------------------------------------
__global__ __launch_bounds__(256) void k_count(const int* __restrict__ dst,
                                               int* __restrict__ deg, int E) {
    const int i = blockIdx.x * blockDim.x + threadIdx.x;
    if (i < E) atomicAdd(&deg[dst[i]], 1);
}

// ---------------- K4: single-block exclusive scan (int4 per thread) -------
__global__ __launch_bounds__(1024) void k_scan(const int* __restrict__ deg,
                                               int* __restrict__ rowptr,
                                               int* __restrict__ cursor, int n) {
    __shared__ int wsum[16];
    __shared__ int carry_s;
    const int tid = threadIdx.x;
    const int lane = tid & 63, wid = tid >> 6;
    if (tid == 0) carry_s = 0;
    __syncthreads();
    for (int base = 0; base < n; base += 4096) {
        const int i0 = base + tid * 4;
        int v0 = 0, v1 = 0, v2 = 0, v3 = 0;
        if (i0 + 3 < n) {
            const int4 v = *(const int4*)&deg[i0];
            v0 = v.x; v1 = v.y; v2 = v.z; v3 = v.w;
        } else if (i0 < n) {
            v0 = deg[i0];
            if (i0 + 1 < n) v1 = deg[i0 + 1];
            if (i0 + 2 < n) v2 = deg[i0 + 2];
        }
        const int tot = v0 + v1 + v2 + v3;
        int incl = tot;
#pragma unroll
        for (int off = 1; off < 64; off <<= 1) {
            const int t = __shfl_up(incl, off);
            if (lane >= off) incl += t;
        }
        if (lane == 63) wsum[wid] = incl;
        __syncthreads();
        if (wid == 0 && lane < 16) {
            int s = wsum[lane];
#pragma unroll
            for (int off = 1; off < 16; off <<= 1) {
                const int t = __shfl_up(s, off);
                if (lane >= off) s += t;
            }
            wsum[lane] = s;
        }
        __syncthreads();
        const int excl = carry_s + (wid ? wsum[wid - 1] : 0) + (incl - tot);
        if (i0 + 3 < n) {
            const int4 o = make_int4(excl, excl + v0, excl + v0 + v1, excl + v0 + v1 + v2);
            *(int4*)&rowptr[i0] = o;
            *(int4*)&cursor[i0] = o;
        } else if (i0 < n) {
            rowptr[i0] = excl; cursor[i0] = excl;
            if (i0 + 1 < n) { rowptr[i0 + 1] = excl + v0; cursor[i0 + 1] = excl + v0; }
            if (i0 + 2 < n) { rowptr[i0 + 2] = excl + v0 + v1; cursor[i0 + 2] = excl + v0 + v1; }
        }
        __syncthreads();
        if (tid == 0) carry_s += wsum[15];
        __syncthreads();
    }
    if (tid == 0) rowptr[n] = carry_s;
}

// ---------------- K5: permute edges into CSR, store packed (src, w) -------
__global__ __launch_bounds__(256) void k_permute(const int* __restrict__ src,
                                                 const int* __restrict__ dst,
                                                 const float* __restrict__ a_s,
                                                 const float* __restrict__ a_d,
                                                 int* __restrict__ cursor,
                                                 int2* __restrict__ sedge, int E) {
    const int i = blockIdx.x * blockDim.x + threadIdx.x;
    if (i >= E) return;
    const int s = src[i], d = dst[i];
    float e = a_s[s] + a_d[d];
    e = e > 0.f ? e : NEG_SLOPE * e;
    const float w = __expf(e);   // max-shift-free: |e| <= ~15 so exp is safe in fp32
    const int pos = atomicAdd(&cursor[d], 1);
    sedge[pos] = make_int2(s, __float_as_int(w));
}

// ---------------- K6: fused gather: weighted sum + normalize + bias -------
__global__ __launch_bounds__(256) void k_gather(const int* __restrict__ rowptr,
                                                const int2* __restrict__ sedge,
                                                const unsigned short* __restrict__ hb,
                                                const float* __restrict__ a_s,
                                                const float* __restrict__ a_d,
                                                const float* __restrict__ bias,
                                                float* __restrict__ out, int n) {
    const int node = (int)((blockIdx.x * (size_t)blockDim.x + threadIdx.x) >> 6);
    const int lane = threadIdx.x & 63;
    if (node >= n) return;
    const int start = rowptr[node], end = rowptr[node + 1];
    const ushort4* hrows = (const ushort4*)hb;   // row stride = 64 ushort4

    float dsum = 0.f;
    float4 acc = make_float4(0.f, 0.f, 0.f, 0.f);
    for (int jb = start; jb < end; jb += 64) {
        const int nthis = min(64, end - jb);
        int sj = 0; float wj = 0.f;
        if (lane < nthis) {
            const int2 p = sedge[jb + lane];
            sj = p.x; wj = __int_as_float(p.y);
        }
        dsum += wj;
        int t = 0;
        for (; t + 4 <= nthis; t += 4) {
            const int s0 = __shfl(sj, t + 0), s1 = __shfl(sj, t + 1);
            const int s2 = __shfl(sj, t + 2), s3 = __shfl(sj, t + 3);
            const float w0 = __shfl(wj, t + 0), w1 = __shfl(wj, t + 1);
            const float w2 = __shfl(wj, t + 2), w3 = __shfl(wj, t + 3);
            const ushort4 r0 = hrows[(size_t)s0 * 64 + lane];
            const ushort4 r1 = hrows[(size_t)s1 * 64 + lane];
            const ushort4 r2 = hrows[(size_t)s2 * 64 + lane];
            const ushort4 r3 = hrows[(size_t)s3 * 64 + lane];
            acc.x = fmaf(w0, bf2f(r0.x), acc.x); acc.y = fmaf(w0, bf2f(r0.y), acc.y);
            acc.z = fmaf(w0, bf2f(r0.z), acc.z); acc.w = fmaf(w0, bf2f(r0.w), acc.w);
            acc.x = fmaf(w1, bf2f(r1.x), acc.x); acc.y = fmaf(w1, bf2f(r1.y), acc.y);
            acc.z = fmaf(w1, bf2f(r1.z), acc.z); acc.w = fmaf(w1, bf2f(r1.w), acc.w);
            acc.x = fmaf(w2, bf2f(r2.x), acc.x); acc.y = fmaf(w2, bf2f(r2.y), acc.y);
            acc.z = fmaf(w2, bf2f(r2.z), acc.z); acc.w = fmaf(w2, bf2f(r2.w), acc.w);
            acc.x = fmaf(w3, bf2f(r3.x), acc.x); acc.y = fmaf(w3, bf2f(r3.y), acc.y);
            acc.z = fmaf(w3, bf2f(r3.z), acc.z); acc.w = fmaf(w3, bf2f(r3.w), acc.w);
        }
        for (; t < nthis; ++t) {
            const int s0 = __shfl(sj, t);
            const float w0 = __shfl(wj, t);
            const ushort4 r0 = hrows[(size_t)s0 * 64 + lane];
            acc.x = fmaf(w0, bf2f(r0.x), acc.x); acc.y = fmaf(w0, bf2f(r0.y), acc.y);
            acc.z = fmaf(w0, bf2f(r0.z), acc.z); acc.w = fmaf(w0, bf2f(r0.w), acc.w);
        }
    }
#pragma unroll
    for (int off = 32; off; off >>= 1) dsum += __shfl_xor(dsum, off);

    // self-loop
    float eself = a_s[node] + a_d[node];
    eself = eself > 0.f ? eself : NEG_SLOPE * eself;
    const float wself = __expf(eself);
    dsum += wself;
    const ushort4 rs = hrows[(size_t)node * 64 + lane];
    acc.x = fmaf(wself, bf2f(rs.x), acc.x); acc.y = fmaf(wself, bf2f(rs.y), acc.y);
    acc.z = fmaf(wself, bf2f(rs.z), acc.z); acc.w = fmaf(wself, bf2f(rs.w), acc.w);

    const float inv = 1.f / dsum;
    const float4 b4 = ((const float4*)bias)[lane];
    float4 o;
    o.x = fmaf(acc.x, inv, b4.x);
    o.y = fmaf(acc.y, inv, b4.y);
    o.z = fmaf(acc.z, inv, b4.z);
    o.w = fmaf(acc.w, inv, b4.w);
    ((float4*)(out + (size_t)node * NODES_C))[lane] = o;
}

extern "C" void kernel_launch(void* const* d_in, const int* in_sizes, int n_in,
                              void* d_out, int out_size, void* d_ws, size_t ws_size,
                              hipStream_t stream) {
    const float* x       = (const float*)d_in[0];
    const int*   edge    = (const int*)d_in[1];
    const float* W       = (const float*)d_in[2];
    const float* att_src = (const float*)d_in[3];
    const float* att_dst = (const float*)d_in[4];
    const float* bias    = (const float*)d_in[5];
    float* out = (float*)d_out;

    const int n = in_sizes[0] / NODES_C;   // 50000
    const int E = in_sizes[1] / 2;         // 1600000
    const int Mpad = (n + 127) & ~127;     // 50048
    const int* src = edge;
    const int* dst = edge + E;

    // workspace carve (256B-aligned blocks)
    char* p = (char*)d_ws;
    auto carve = [&p](size_t bytes) { char* r = p; p += (bytes + 255) & ~(size_t)255; return r; };
    unsigned short* xb = (unsigned short*)carve((size_t)Mpad * NODES_C * 2);  // 25.6 MB
    unsigned short* wt = (unsigned short*)carve((size_t)NODES_C * NODES_C * 2);
    unsigned short* hb = (unsigned short*)carve((size_t)n * NODES_C * 2);     // 25.6 MB
    float* a_s   = (float*)carve((size_t)n * 4);
    float* a_d   = (float*)carve((size_t)n * 4);
    int*   deg    = (int*)carve((size_t)n * 4);
    int*   rowptr = (int*)carve((size_t)(n + 1) * 4);
    int*   cursor = (int*)carve((size_t)n * 4);
    int2*  sedge  = (int2*)carve((size_t)E * 8);                              // 12.8 MB

    hipMemsetAsync(deg, 0, (size_t)n * 4, stream);

    const int valid4 = n * (NODES_C / 4), total4 = Mpad * (NODES_C / 4);
    k_cvt_x<<<(total4 + 255) / 256, 256, 0, stream>>>(x, xb, valid4, total4);
    k_cvt_w<<<(NODES_C * NODES_C) / 256, 256, 0, stream>>>(W, wt);
    k_count<<<(E + 255) / 256, 256, 0, stream>>>(dst, deg, E);
    k_gemm_mfma<<<(Mpad / 128) * 2, 256, 0, stream>>>(xb, wt, hb, n);
    k_node_att<<<(n + 3) / 4, 256, 0, stream>>>(hb, att_src, att_dst, a_s, a_d, n);
    k_scan<<<1, 1024, 0, stream>>>(deg, rowptr, cursor, n);
    k_permute<<<(E + 255) / 256, 256, 0, stream>>>(src, dst, a_s, a_d, cursor, sedge, E);
    k_gather<<<(n + 3) / 4, 256, 0, stream>>>(rowptr, sedge, hb, a_s, a_d, bias, out, n);
}

// Round 4
// 304.190 us; speedup vs baseline: 18.5780x; 1.0613x over previous
//
#include <hip/hip_runtime.h>
#include <math.h>

#define NODES_C 256
#define NEG_SLOPE 0.2f

typedef __attribute__((ext_vector_type(8))) short short8;
typedef __attribute__((ext_vector_type(4))) float f32x4;

__device__ inline unsigned short f2bf(float f) {   // RNE float->bf16
    unsigned u = __float_as_uint(f);
    u = (u + 0x7fff + ((u >> 16) & 1)) >> 16;
    return (unsigned short)u;
}
__device__ inline float bf2f(unsigned short u) {
    return __uint_as_float((unsigned)u << 16);
}
__device__ inline void gload_lds16(const void* g, void* l) {
    __builtin_amdgcn_global_load_lds(
        (const __attribute__((address_space(1))) unsigned int*)g,
        (__attribute__((address_space(3))) unsigned int*)l, 16, 0, 0);
}

// ============ Stage A (fat): count || cvt_w || cvt_x =====================
// roles by block range; count first so its atomics start earliest.
__global__ __launch_bounds__(256) void k_stageA(
    const float* __restrict__ x, const float* __restrict__ W,
    const int* __restrict__ dst,
    unsigned short* __restrict__ xb, unsigned short* __restrict__ wt,
    int* __restrict__ deg,
    int valid4, int total4, int nbCount, int nbCvtw, int E) {
    const int tid = threadIdx.x;
    int bid = blockIdx.x;
    if (bid < nbCount) {                       // ---- degree count ----
        const int base = bid * 1024 + tid;
#pragma unroll
        for (int k = 0; k < 4; ++k) {
            const int i = base + k * 256;
            if (i < E) atomicAdd(&deg[dst[i]], 1);
        }
        return;
    }
    bid -= nbCount;
    if (bid < nbCvtw) {                        // ---- W -> wt (bf16, transposed) ----
        const int base = bid * 1024 + tid;
#pragma unroll
        for (int k = 0; k < 4; ++k) {
            const int i = base + k * 256;      // flat [nn][kk] out index
            wt[i] = f2bf(W[(i & 255) * NODES_C + (i >> 8)]);
        }
        return;
    }
    bid -= nbCvtw;                             // ---- x -> xb (bf16, zero-pad) ----
    const int base = bid * 1024 + tid;
#pragma unroll
    for (int k = 0; k < 4; ++k) {
        const int i = base + k * 256;
        if (i >= total4) continue;
        ushort4 o = {0, 0, 0, 0};
        if (i < valid4) {
            const float4 v = ((const float4*)x)[i];
            o.x = f2bf(v.x); o.y = f2bf(v.y); o.z = f2bf(v.z); o.w = f2bf(v.w);
        }
        ((ushort4*)xb)[i] = o;
    }
}

// ============ Stage B (fat): scan (block 0) || gemm+attn (blocks 1..) =====
__global__ __launch_bounds__(256) void k_stageB(
    const unsigned short* __restrict__ xb, const unsigned short* __restrict__ wt,
    const float* __restrict__ att_src, const float* __restrict__ att_dst,
    unsigned short* __restrict__ hb, float* __restrict__ a_s, float* __restrict__ a_d,
    const int* __restrict__ deg, int* __restrict__ rowptr, int* __restrict__ cursor,
    int n) {
    __shared__ unsigned short Ab[128 * 32];
    __shared__ unsigned short Bb[128 * 32];
    __shared__ float pfs[2][128], pfd[2][128];
    __shared__ int wsum[4];
    __shared__ int carry_s;
    const int tid = threadIdx.x;
    const int lane = tid & 63;
    const int wid = tid >> 6;

    if (blockIdx.x == 0) {
        // ---------------- scan role: exclusive prefix over deg -----------
        if (tid == 0) carry_s = 0;
        __syncthreads();
        for (int bs = 0; bs < n; bs += 4096) {
            const int i0 = bs + tid * 16;
            int v[16];
#pragma unroll
            for (int k = 0; k < 16; k += 4) {
                const int idx = i0 + k;
                if (idx + 3 < n) {
                    const int4 t4 = *(const int4*)&deg[idx];
                    v[k] = t4.x; v[k + 1] = t4.y; v[k + 2] = t4.z; v[k + 3] = t4.w;
                } else {
                    v[k]     = (idx     < n) ? deg[idx]     : 0;
                    v[k + 1] = (idx + 1 < n) ? deg[idx + 1] : 0;
                    v[k + 2] = (idx + 2 < n) ? deg[idx + 2] : 0;
                    v[k + 3] = (idx + 3 < n) ? deg[idx + 3] : 0;
                }
            }
            int tot = 0;
#pragma unroll
            for (int k = 0; k < 16; ++k) tot += v[k];
            int incl = tot;
#pragma unroll
            for (int off = 1; off < 64; off <<= 1) {
                const int t = __shfl_up(incl, off);
                if (lane >= off) incl += t;
            }
            if (lane == 63) wsum[wid] = incl;
            __syncthreads();
            if (tid < 4) {
                int s = wsum[tid];
#pragma unroll
                for (int off = 1; off < 4; off <<= 1) {
                    const int t = __shfl_up(s, off);
                    if (tid >= off) s += t;
                }
                wsum[tid] = s;
            }
            __syncthreads();
            int run = carry_s + (wid ? wsum[wid - 1] : 0) + incl - tot;
            int o[16];
#pragma unroll
            for (int k = 0; k < 16; ++k) { o[k] = run; run += v[k]; }
#pragma unroll
            for (int k = 0; k < 16; k += 4) {
                const int idx = i0 + k;
                if (idx + 3 < n) {
                    const int4 t4 = make_int4(o[k], o[k + 1], o[k + 2], o[k + 3]);
                    *(int4*)&rowptr[idx] = t4;
                    *(int4*)&cursor[idx] = t4;
                } else {
                    if (idx < n)     { rowptr[idx] = o[k];     cursor[idx] = o[k]; }
                    if (idx + 1 < n) { rowptr[idx + 1] = o[k + 1]; cursor[idx + 1] = o[k + 1]; }
                    if (idx + 2 < n) { rowptr[idx + 2] = o[k + 2]; cursor[idx + 2] = o[k + 2]; }
                }
            }
            __syncthreads();
            if (tid == 0) carry_s += wsum[3];
            __syncthreads();
        }
        if (tid == 0) rowptr[n] = carry_s;
        return;
    }

    // ---------------- gemm role: 128x128 tile, fused attn epilogue -------
    const int gbid = blockIdx.x - 1;
    const int wr = wid >> 1, wc = wid & 1;
    const int brow = (gbid >> 1) * 128;
    const int bcol = (gbid & 1) * 128;
    const int rsel = lane & 15, ksel = (lane >> 4) * 8;

    // attention vector slices for this wave's columns (overlap with K loop)
    float avs[4], avd[4];
#pragma unroll
    for (int q = 0; q < 4; ++q) {
        avs[q] = att_src[bcol + wc * 64 + q * 16 + rsel];
        avd[q] = att_dst[bcol + wc * 64 + q * 16 + rsel];
    }

    f32x4 acc[4][4] = {};
    const int c0 = wid, c1 = wid + 4;
    const int srow0 = c0 * 16 + (lane >> 2), srow1 = c1 * 16 + (lane >> 2);
    const int sk = (lane & 3) * 8;

    for (int kk = 0; kk < 256; kk += 32) {
        gload_lds16(xb + (size_t)(brow + srow0) * NODES_C + kk + sk, Ab + c0 * 512);
        gload_lds16(xb + (size_t)(brow + srow1) * NODES_C + kk + sk, Ab + c1 * 512);
        gload_lds16(wt + (size_t)(bcol + srow0) * NODES_C + kk + sk, Bb + c0 * 512);
        gload_lds16(wt + (size_t)(bcol + srow1) * NODES_C + kk + sk, Bb + c1 * 512);
        __syncthreads();
        short8 afrag[4], bfrag[4];
#pragma unroll
        for (int m = 0; m < 4; ++m)
            afrag[m] = *(const short8*)&Ab[(wr * 64 + m * 16 + rsel) * 32 + ksel];
#pragma unroll
        for (int q = 0; q < 4; ++q)
            bfrag[q] = *(const short8*)&Bb[(wc * 64 + q * 16 + rsel) * 32 + ksel];
#pragma unroll
        for (int m = 0; m < 4; ++m)
#pragma unroll
            for (int q = 0; q < 4; ++q)
                acc[m][q] = __builtin_amdgcn_mfma_f32_16x16x32_bf16(afrag[m], bfrag[q], acc[m][q], 0, 0, 0);
        __syncthreads();
    }

    // epilogue: hb store + per-row partial dots vs att vectors
    const int rbase = (lane >> 4) * 4;
#pragma unroll
    for (int m = 0; m < 4; ++m) {
#pragma unroll
        for (int j = 0; j < 4; ++j) {
            float s = acc[m][0][j] * avs[0] + acc[m][1][j] * avs[1]
                    + acc[m][2][j] * avs[2] + acc[m][3][j] * avs[3];
            float d = acc[m][0][j] * avd[0] + acc[m][1][j] * avd[1]
                    + acc[m][2][j] * avd[2] + acc[m][3][j] * avd[3];
#pragma unroll
            for (int off = 1; off < 16; off <<= 1) {   // reduce across the 16 col-lanes
                s += __shfl_xor(s, off);
                d += __shfl_xor(d, off);
            }
            const int rloc = wr * 64 + m * 16 + rbase + j;
            if (rsel == 0) { pfs[wc][rloc] = s; pfd[wc][rloc] = d; }
            const int r = brow + rloc;
            if (r < n) {
#pragma unroll
                for (int q = 0; q < 4; ++q)
                    hb[(size_t)r * NODES_C + bcol + wc * 64 + q * 16 + rsel] = f2bf(acc[m][q][j]);
            }
        }
    }
    __syncthreads();
    if (tid < 128) {
        const int r = brow + tid;
        if (r < n) atomicAdd(&a_s[r], pfs[0][tid] + pfs[1][tid]);
    } else {
        const int t2 = tid - 128;
        const int r = brow + t2;
        if (r < n) atomicAdd(&a_d[r], pfd[0][t2] + pfd[1][t2]);
    }
}

// ============ permute edges into CSR, store packed (src, w) ==============
__global__ __launch_bounds__(256) void k_permute(const int* __restrict__ src,
                                                 const int* __restrict__ dst,
                                                 const float* __restrict__ a_s,
                                                 const float* __restrict__ a_d,
                                                 int* __restrict__ cursor,
                                                 int2* __restrict__ sedge, int E) {
    const int i = blockIdx.x * blockDim.x + threadIdx.x;
    if (i >= E) return;
    const int s = src[i], d = dst[i];
    float e = a_s[s] + a_d[d];
    e = e > 0.f ? e : NEG_SLOPE * e;
    const float w = __expf(e);   // |e| small: exp safe in fp32; softmax is shift-invariant
    const int pos = atomicAdd(&cursor[d], 1);
    sedge[pos] = make_int2(s, __float_as_int(w));
}

// ============ fused gather: weighted sum + normalize + bias ==============
__global__ __launch_bounds__(256) void k_gather(const int* __restrict__ rowptr,
                                                const int2* __restrict__ sedge,
                                                const unsigned short* __restrict__ hb,
                                                const float* __restrict__ a_s,
                                                const float* __restrict__ a_d,
                                                const float* __restrict__ bias,
                                                float* __restrict__ out, int n) {
    const int node = (int)((blockIdx.x * (size_t)blockDim.x + threadIdx.x) >> 6);
    const int lane = threadIdx.x & 63;
    if (node >= n) return;
    const int start = rowptr[node], end = rowptr[node + 1];
    const ushort4* hrows = (const ushort4*)hb;   // row stride = 64 ushort4

    float dsum = 0.f;
    float4 acc = make_float4(0.f, 0.f, 0.f, 0.f);
    for (int jb = start; jb < end; jb += 64) {
        const int nthis = min(64, end - jb);
        int sj = 0; float wj = 0.f;
        if (lane < nthis) {
            const int2 p = sedge[jb + lane];
            sj = p.x; wj = __int_as_float(p.y);
        }
        dsum += wj;
        int t = 0;
        for (; t + 8 <= nthis; t += 8) {
            int ss[8]; float ww[8];
#pragma unroll
            for (int k = 0; k < 8; ++k) {
                ss[k] = __shfl(sj, t + k);
                ww[k] = __shfl(wj, t + k);
            }
            ushort4 rr[8];
#pragma unroll
            for (int k = 0; k < 8; ++k) rr[k] = hrows[(size_t)ss[k] * 64 + lane];
#pragma unroll
            for (int k = 0; k < 8; ++k) {
                acc.x = fmaf(ww[k], bf2f(rr[k].x), acc.x);
                acc.y = fmaf(ww[k], bf2f(rr[k].y), acc.y);
                acc.z = fmaf(ww[k], bf2f(rr[k].z), acc.z);
                acc.w = fmaf(ww[k], bf2f(rr[k].w), acc.w);
            }
        }
        for (; t < nthis; ++t) {
            const int s0 = __shfl(sj, t);
            const float w0 = __shfl(wj, t);
            const ushort4 r0 = hrows[(size_t)s0 * 64 + lane];
            acc.x = fmaf(w0, bf2f(r0.x), acc.x);
            acc.y = fmaf(w0, bf2f(r0.y), acc.y);
            acc.z = fmaf(w0, bf2f(r0.z), acc.z);
            acc.w = fmaf(w0, bf2f(r0.w), acc.w);
        }
    }
#pragma unroll
    for (int off = 32; off; off >>= 1) dsum += __shfl_xor(dsum, off);

    // self-loop contribution
    float eself = a_s[node] + a_d[node];
    eself = eself > 0.f ? eself : NEG_SLOPE * eself;
    const float wself = __expf(eself);
    dsum += wself;
    const ushort4 rs = hrows[(size_t)node * 64 + lane];
    acc.x = fmaf(wself, bf2f(rs.x), acc.x);
    acc.y = fmaf(wself, bf2f(rs.y), acc.y);
    acc.z = fmaf(wself, bf2f(rs.z), acc.z);
    acc.w = fmaf(wself, bf2f(rs.w), acc.w);

    const float inv = 1.f / dsum;
    const float4 b4 = ((const float4*)bias)[lane];
    float4 o;
    o.x = fmaf(acc.x, inv, b4.x);
    o.y = fmaf(acc.y, inv, b4.y);
    o.z = fmaf(acc.z, inv, b4.z);
    o.w = fmaf(acc.w, inv, b4.w);
    ((float4*)(out + (size_t)node * NODES_C))[lane] = o;
}

extern "C" void kernel_launch(void* const* d_in, const int* in_sizes, int n_in,
                              void* d_out, int out_size, void* d_ws, size_t ws_size,
                              hipStream_t stream) {
    const float* x       = (const float*)d_in[0];
    const int*   edge    = (const int*)d_in[1];
    const float* W       = (const float*)d_in[2];
    const float* att_src = (const float*)d_in[3];
    const float* att_dst = (const float*)d_in[4];
    const float* bias    = (const float*)d_in[5];
    float* out = (float*)d_out;

    const int n = in_sizes[0] / NODES_C;   // 50000
    const int E = in_sizes[1] / 2;         // 1600000
    const int Mpad = (n + 127) & ~127;     // 50048
    const int* src = edge;
    const int* dst = edge + E;

    // workspace carve (256B-aligned blocks)
    char* p = (char*)d_ws;
    auto carve = [&p](size_t bytes) { char* r = p; p += (bytes + 255) & ~(size_t)255; return r; };
    unsigned short* xb = (unsigned short*)carve((size_t)Mpad * NODES_C * 2);  // 25.6 MB
    unsigned short* wt = (unsigned short*)carve((size_t)NODES_C * NODES_C * 2);
    unsigned short* hb = (unsigned short*)carve((size_t)n * NODES_C * 2);     // 25.6 MB
    float* a_s = (float*)carve((size_t)n * 4 * 3);   // a_s | a_d | deg contiguous (one memset)
    float* a_d = a_s + n;
    int*   deg = (int*)(a_d + n);
    int*   rowptr = (int*)carve((size_t)(n + 1) * 4);
    int*   cursor = (int*)carve((size_t)n * 4);
    int2*  sedge  = (int2*)carve((size_t)E * 8);                              // 12.8 MB

    // zero a_s, a_d (atomic targets) and deg in one shot
    hipMemsetAsync(a_s, 0, (size_t)n * 12, stream);

    const int valid4 = n * (NODES_C / 4);
    const int total4 = Mpad * (NODES_C / 4);
    const int nbCount = (E + 1023) / 1024;                    // 1563
    const int nbCvtw  = (NODES_C * NODES_C) / 1024;           // 64
    const int nbCvtx  = (total4 + 1023) / 1024;               // 3128

    k_stageA<<<nbCount + nbCvtw + nbCvtx, 256, 0, stream>>>(
        x, W, dst, xb, wt, deg, valid4, total4, nbCount, nbCvtw, E);
    k_stageB<<<1 + (Mpad / 128) * 2, 256, 0, stream>>>(
        xb, wt, att_src, att_dst, hb, a_s, a_d, deg, rowptr, cursor, n);
    k_permute<<<(E + 255) / 256, 256, 0, stream>>>(src, dst, a_s, a_d, cursor, sedge, E);
    k_gather<<<(n + 3) / 4, 256, 0, stream>>>(rowptr, sedge, hb, a_s, a_d, bias, out, n);
}